// Round 3
// baseline (501.850 us; speedup 1.0000x reference)
//
#include <hip/hip_runtime.h>

// Bilinear grid sample, B=8 H=512 W=512 C=32, fp32 — two-pass source-binned.
//
// R1/R2 post-mortem: nt-store null, 2x MLP null -> throughput wall at
// ~3.9 TB/s on the L2-miss path with FETCH_SIZE pinned at 487 MB
// (demand 1.07 GB, hit 55%, compulsory floor 273 MB -> 214 MB re-fetch).
// Random gathers scatter the x4 line-reuse across time and XCDs.
//
// This version reorders work by SOURCE y-band so reuse is captured in L2:
//  pass 1: bin pixels by (batch, y0c>>5) -> 128 bins; entries {x,y,pix}.
//  pass 2: bin k runs on XCD k%8 only (bid%8 == XCD round-robin, measured);
//          band working set 33 rows x 64KB = 2.1 MB fits one XCD's 4MB L2.
// Prediction: pass2 FETCH ~300 MB (was 487), combined dur 150-180 us.

#define NBINS 128u          // 8 batches x 16 y-bands (32 rows each)
#define CAP   20480u        // per-bin entry capacity (mean 16384, +33 sigma)
#define ENT_OFF 4096        // byte offset of entries[] in workspace

__device__ __forceinline__ void bilinear_px(
    const float* __restrict__ ibase,  // img + batch offset
    float* __restrict__ out, unsigned pix, float x, float y, unsigned c)
{
    const int x0 = (int)floorf(x);
    const int y0 = (int)floorf(y);
    const int x0c = min(max(x0,     0), 511);
    const int x1c = min(max(x0 + 1, 0), 511);
    const int y0c = min(max(y0,     0), 511);
    const int y1c = min(max(y0 + 1, 0), 511);

    // issue row y0's two adjacent lines first, then row y1's (DRAM row locality)
    const float4 Ia = *reinterpret_cast<const float4*>(ibase + (unsigned)(y0c*512 + x0c)*32u + c);
    const float4 Ic = *reinterpret_cast<const float4*>(ibase + (unsigned)(y0c*512 + x1c)*32u + c);
    const float4 Ib = *reinterpret_cast<const float4*>(ibase + (unsigned)(y1c*512 + x0c)*32u + c);
    const float4 Id = *reinterpret_cast<const float4*>(ibase + (unsigned)(y1c*512 + x1c)*32u + c);

    const float wa = ((float)x1c - x) * ((float)y1c - y);
    const float wb = ((float)x1c - x) * (y - (float)y0c);
    const float wc = (x - (float)x0c) * ((float)y1c - y);
    const float wd = (x - (float)x0c) * (y - (float)y0c);

    float4 o;
    o.x = wa*Ia.x + wb*Ib.x + wc*Ic.x + wd*Id.x;
    o.y = wa*Ia.y + wb*Ib.y + wc*Ic.y + wd*Id.y;
    o.z = wa*Ia.z + wb*Ib.z + wc*Ic.z + wd*Id.z;
    o.w = wa*Ia.w + wb*Ib.w + wc*Ic.w + wd*Id.w;
    *reinterpret_cast<float4*>(out + (size_t)pix*32u + c) = o;
}

// ---------------- pass 1: bin pixels by (batch, y-band) ----------------
// 2048 blocks x 256 thr, 4 px/thread, 1024 contiguous px per block (1 batch).
__global__ __launch_bounds__(256) void gs_bin(
    const float* __restrict__ grid,
    const float* __restrict__ img,
    float* __restrict__ out,
    unsigned* __restrict__ gcnt,
    float4* __restrict__ entries)
{
    __shared__ unsigned lcnt[16];
    __shared__ unsigned lbase[16];
    const unsigned tid = threadIdx.x;
    if (tid < 16) lcnt[tid] = 0;
    __syncthreads();

    const unsigned blockbase = blockIdx.x << 10;
    const unsigned batch = blockbase >> 18;

    float xs[4], ys[4];
    unsigned bandk[4], slotk[4], pixk[4];
    #pragma unroll
    for (int k = 0; k < 4; ++k) {
        const unsigned pix = blockbase + tid + ((unsigned)k << 8);
        const float2 g = *reinterpret_cast<const float2*>(grid + (size_t)pix * 2u);
        const float x = 0.5f * ((g.x + 1.0f) * 511.0f);
        const float y = 0.5f * ((g.y + 1.0f) * 511.0f);
        const int y0 = (int)floorf(y);
        const int y0c = min(max(y0, 0), 511);
        const unsigned band = (unsigned)y0c >> 5;
        slotk[k] = atomicAdd(&lcnt[band], 1u);
        bandk[k] = band; pixk[k] = pix; xs[k] = x; ys[k] = y;
    }
    __syncthreads();
    if (tid < 16) lbase[tid] = atomicAdd(&gcnt[batch * 16u + tid], lcnt[tid]);
    __syncthreads();

    const float* ibase = img + (((size_t)batch << 18) * 32u);
    #pragma unroll
    for (int k = 0; k < 4; ++k) {
        const unsigned idx = lbase[bandk[k]] + slotk[k];
        const unsigned bin = batch * 16u + bandk[k];
        if (idx < CAP) {
            float4 e;
            e.x = xs[k]; e.y = ys[k];
            e.z = __uint_as_float(pixk[k]); e.w = 0.0f;
            entries[(size_t)bin * CAP + idx] = e;
        } else {
            // capacity overflow (P ~ 0): compute this pixel directly
            for (unsigned c = 0; c < 32; c += 4)
                bilinear_px(ibase, out, pixk[k], xs[k], ys[k], c);
        }
    }
}

// ---------------- pass 2: apply, bin k pinned to XCD k%8 ----------------
// 65536 blocks x 256 thr; 8 lanes per pixel (float4 of channels).
__global__ __launch_bounds__(256) void gs_apply(
    const float* __restrict__ img,
    float* __restrict__ out,
    const unsigned* __restrict__ gcnt,
    const float4* __restrict__ entries)
{
    const unsigned bid = blockIdx.x;
    const unsigned xcd      = bid & 7u;
    const unsigned j        = bid >> 3;
    const unsigned ord      = j >> 9;      // 0..15: sequential bins per XCD
    const unsigned blkInBin = j & 511u;
    const unsigned bin   = ord * 8u + xcd; // bin % 8 == xcd
    const unsigned batch = bin >> 4;

    unsigned n = gcnt[bin];
    if (n > CAP) n = CAP;

    const unsigned tid = threadIdx.x;
    const unsigned grp = tid >> 3;         // 0..31 pixels per block-iter
    const unsigned c   = (tid & 7u) << 2;  // channel start
    const float* ibase = img + (((size_t)batch << 18) * 32u);

    for (unsigned p = blkInBin * 32u + grp; p < n; p += 16384u) {
        const float4 e = entries[(size_t)bin * CAP + p];
        bilinear_px(ibase, out, __float_as_uint(e.z), e.x, e.y, c);
    }
}

// ---------------- fallback: proven single-pass (R0) ----------------
__global__ __launch_bounds__(256) void gs_direct(
    const float* __restrict__ img,
    const float* __restrict__ grid,
    float* __restrict__ out)
{
    const unsigned gid = blockIdx.x * 256u + threadIdx.x;
    const unsigned pix = gid >> 3;
    const unsigned c   = (gid & 7u) << 2;
    const float2 g = *reinterpret_cast<const float2*>(grid + (size_t)pix * 2u);
    const float x = 0.5f * ((g.x + 1.0f) * 511.0f);
    const float y = 0.5f * ((g.y + 1.0f) * 511.0f);
    const unsigned batch = pix >> 18;
    const float* ibase = img + (((size_t)batch << 18) * 32u);
    bilinear_px(ibase, out, pix, x, y, c);
}

extern "C" void kernel_launch(void* const* d_in, const int* in_sizes, int n_in,
                              void* d_out, int out_size, void* d_ws, size_t ws_size,
                              hipStream_t stream) {
    const float* img  = (const float*)d_in[0];
    const float* grid = (const float*)d_in[1];
    float* out = (float*)d_out;

    const size_t need = (size_t)ENT_OFF + (size_t)NBINS * CAP * sizeof(float4); // ~42 MB
    if (d_ws != nullptr && ws_size >= need) {
        unsigned* gcnt  = (unsigned*)d_ws;
        float4* entries = (float4*)((char*)d_ws + ENT_OFF);
        hipMemsetAsync(gcnt, 0, NBINS * sizeof(unsigned), stream);
        gs_bin<<<2048, 256, 0, stream>>>(grid, img, out, gcnt, entries);
        gs_apply<<<65536, 256, 0, stream>>>(img, out, gcnt, entries);
    } else {
        gs_direct<<<65536, 256, 0, stream>>>(img, grid, out);
    }
}